// Round 8
// baseline (65.340 us; speedup 1.0000x reference)
//
#include <hip/hip_runtime.h>

#define HH 512
#define WW 512
#define CH 3
#define NTX 64           // one column per lane -> lane-stride-1 LDS (proven conflict-free)
#define NTY 2            // 128-thread blocks -> 4096 blocks = 2 residency rounds (tail fix)
#define PY  4            // vertical pixels per thread
#define SPANY (NTY * PY)         // 8 rows per block
#define TILE_W 70                // 64 + 6 halo
#define TILE_H (SPANY + 6)       // 14
#define CSTR (TILE_H * TILE_W)   // channel stride in floats (980)

// exp(-50*d^2 - ((i-3)^2+(j-3)^2)/4.5) == exp2(K1*d^2 + K2*(i-3)^2) * WJ[j]
#define K1f (-72.13475204444817f)   // -50 * log2(e)
#define K2f (-0.3205988979753252f)  // -(1/4.5) * log2(e)

__device__ __constant__ const float WJ[7] = {
    0.13533528323661270f,  // exp(-9/4.5)
    0.41111229050718745f,  // exp(-4/4.5)
    0.80073740291680804f,  // exp(-1/4.5)
    1.0f,
    0.80073740291680804f,
    0.41111229050718745f,
    0.13533528323661270f
};

__device__ __forceinline__ int reflect_idx(int v, int n) {
    v = (v < 0) ? -v : v;
    return (v >= n) ? (2 * (n - 1) - v) : v;
}

__device__ __forceinline__ float fast_exp2(float x) {
#if __has_builtin(__builtin_amdgcn_exp2f)
    return __builtin_amdgcn_exp2f(x);
#else
    return exp2f(x);
#endif
}

__global__ __launch_bounds__(NTX * NTY)
void bilateral_kernel(const float* __restrict__ in, float* __restrict__ out) {
    __shared__ float sm[CH * CSTR];   // 11760 B

    const int bx0 = blockIdx.x * NTX;
    const int by0 = blockIdx.y * SPANY;
    const int b   = blockIdx.z;
    const int lx  = threadIdx.x;
    const float* inb = in + (size_t)b * CH * HH * WW;

    // ---- cooperative halo staging (lane-stride-1 b32 writes: conflict-free) ----
    for (int c = 0; c < CH; ++c) {
        for (int ty = threadIdx.y; ty < TILE_H; ty += NTY) {
            const int gy = reflect_idx(by0 + ty - 3, HH);
            const float* grow = inb + (c * HH + gy) * WW;
            float* srow = &sm[c * CSTR + ty * TILE_W];
            const int gx0 = reflect_idx(bx0 + lx - 3, WW);
            srow[lx] = grow[gx0];
            if (lx < TILE_W - NTX) {
                const int gx1 = reflect_idx(bx0 + lx + NTX - 3, WW);
                srow[lx + NTX] = grow[gx1];
            }
        }
    }
    __syncthreads();

    const int rb = threadIdx.y * PY;            // first pixel row (tile coords)
    const float* smb = sm + rb * TILE_W + lx;   // single per-lane base

    // center values (compile-time offsets)
    float c0[PY], c1[PY], c2[PY];
#pragma unroll
    for (int py = 0; py < PY; ++py) {
        c0[py] = smb[0 * CSTR + (py + 3) * TILE_W + 3];
        c1[py] = smb[1 * CSTR + (py + 3) * TILE_W + 3];
        c2[py] = smb[2 * CSTR + (py + 3) * TILE_W + 3];
    }

    float n0[PY] = {}, n1[PY] = {}, n2[PY] = {}, den[PY] = {};

    const float* rowp = smb;
    // unroll 2: double-buffers next row's ds_reads against current row's taps,
    // while keeping the live set bounded (~2x21 + fixed) unlike full unroll (R5: 204 VGPR)
#pragma unroll 2
    for (int r = 0; r < PY + 6; ++r) {
        float A0[7], A1[7], A2[7];
#pragma unroll
        for (int j = 0; j < 7; ++j) {
            A0[j] = rowp[0 * CSTR + j];
            A1[j] = rowp[1 * CSTR + j];
            A2[j] = rowp[2 * CSTR + j];
        }
#pragma unroll
        for (int py = 0; py < PY; ++py) {
            const int i = r - py;                 // kernel row for pixel-row py (wave-uniform)
            if (0 <= i && i <= 6) {
                const int im3 = i - 3;
                const float ikK2 = (float)(im3 * im3) * K2f;
#pragma unroll
                for (int j = 0; j < 7; ++j) {
                    const float v0 = A0[j], v1 = A1[j], v2 = A2[j];
                    const float d  = fabsf(v0 - c0[py]) + fabsf(v1 - c1[py]) + fabsf(v2 - c2[py]);
                    const float wp = fast_exp2(fmaf(d * K1f, d, ikK2));
                    const float w  = wp * WJ[j];
                    n0[py]  = fmaf(w, v0, n0[py]);
                    n1[py]  = fmaf(w, v1, n1[py]);
                    n2[py]  = fmaf(w, v2, n2[py]);
                    den[py] += w;
                }
            }
        }
        rowp += TILE_W;
    }

    float* outb = out + (size_t)b * CH * HH * WW;
    const int x = bx0 + lx;
#pragma unroll
    for (int py = 0; py < PY; ++py) {
        const int y = by0 + rb + py;
        const float inv = 1.0f / den[py];   // den >= 1 (center tap w == 1)
        outb[(0 * HH + y) * WW + x] = n0[py] * inv;
        outb[(1 * HH + y) * WW + x] = n1[py] * inv;
        outb[(2 * HH + y) * WW + x] = n2[py] * inv;
    }
}

extern "C" void kernel_launch(void* const* d_in, const int* in_sizes, int n_in,
                              void* d_out, int out_size, void* d_ws, size_t ws_size,
                              hipStream_t stream) {
    const float* in = (const float*)d_in[0];
    float* out = (float*)d_out;
    const int B = in_sizes[0] / (CH * HH * WW);
    dim3 grid(WW / NTX, HH / SPANY, B);
    dim3 block(NTX, NTY, 1);
    bilateral_kernel<<<grid, block, 0, stream>>>(in, out);
}